// Round 2
// baseline (259.439 us; speedup 1.0000x reference)
//
#include <hip/hip_runtime.h>

// Problem constants (fixed by reference)
#define NAG   16
#define OBSD  256
#define ACTD  32
#define BB    16
#define TT    64
#define SCF   16
#define H1D   128
#define H2D   64
#define BT    (BB*TT)       // 1024
#define NTOK  (BT*NAG)      // 16384
#define NEVAL 18            // with + zero + 16 cf

typedef float f4 __attribute__((ext_vector_type(4)));

// ---------------------------------------------------------------------------
// Kernel 1: h1_obs[g][j] = b1[j] + sum_d obs[g][d] * W1[d][j]   (d = 0..255)
// M=16384, N=128, K=256.  BM=32, BN=128, BK=32, 256 threads, grid 512.
// ---------------------------------------------------------------------------
__global__ __launch_bounds__(256) void k_h1obs(
    const float* __restrict__ obs, const float* __restrict__ W1,
    const float* __restrict__ b1, float* __restrict__ h1obs)
{
    __shared__ float As[32][36];      // 32 rows x 32 k (pad 36)
    __shared__ float Bs[32 * 128];    // 32 k x 128 j, flat

    const int tid = threadIdx.x;
    const int g0  = blockIdx.x * 32;
    const int rb  = tid >> 5;         // 0..7
    const int cb  = tid & 31;         // 0..31
    const int r0  = rb * 4;
    const int c0  = cb * 4;
    const int arow = tid >> 3;        // 0..31
    const int akk  = (tid & 7) * 4;   // 0..28

    float acc[4][4] = {};

    for (int kt = 0; kt < OBSD; kt += 32) {
        // stage A: obs rows g0..g0+31, k = kt..kt+31
        f4 av = *(const f4*)(obs + (g0 + arow) * OBSD + kt + akk);
        *(f4*)(&As[arow][akk]) = av;
        // stage B: W1 rows kt..kt+31 (contiguous 4096 floats)
        const float* wsrc = W1 + kt * H1D;
        #pragma unroll
        for (int u = 0; u < 4; ++u) {
            f4 bv = *(const f4*)(wsrc + u * 1024 + tid * 4);
            *(f4*)(Bs + u * 1024 + tid * 4) = bv;
        }
        __syncthreads();
        #pragma unroll
        for (int k0 = 0; k0 < 32; k0 += 4) {
            f4 a[4], b[4];
            #pragma unroll
            for (int i = 0; i < 4; ++i) a[i] = *(const f4*)(&As[r0 + i][k0]);
            #pragma unroll
            for (int kk = 0; kk < 4; ++kk) b[kk] = *(const f4*)(Bs + (k0 + kk) * H1D + c0);
            #pragma unroll
            for (int i = 0; i < 4; ++i)
                #pragma unroll
                for (int kk = 0; kk < 4; ++kk)
                    #pragma unroll
                    for (int j = 0; j < 4; ++j)
                        acc[i][j] = fmaf(a[i][kk], b[kk][j], acc[i][j]);
        }
        __syncthreads();
    }

    f4 bias = *(const f4*)(b1 + c0);
    #pragma unroll
    for (int i = 0; i < 4; ++i) {
        f4 v;
        #pragma unroll
        for (int j = 0; j < 4; ++j) v[j] = acc[i][j] + bias[j];
        *(f4*)(h1obs + (g0 + r0 + i) * H1D + c0) = v;
    }
}

// ---------------------------------------------------------------------------
// Kernel 2: per block = 32 tokens. For e in 0..17:
//   h1 = relu(h1_obs + act_e @ W1a);  h2 = relu(h1 @ W2 + b2);  p = h2 @ W3 + b3
//   e==0 -> p_with ;  e>=1 -> accumulate p_without (e==1 is the zero action).
// Then KL(softmax(p_wo) || ...) per token, mean over 32 -> out[g].
// LDS: 4.5K act + 16K W1a + 32K W2 + 16.5K h1 + 8.5K h2 = 77.5 KB -> 2 blk/CU
// ---------------------------------------------------------------------------
__global__ __launch_bounds__(256) void k_main(
    const float* __restrict__ actions, const float* __restrict__ cf,
    const float* __restrict__ W1, const float* __restrict__ W2,
    const float* __restrict__ b2v, const float* __restrict__ W3,
    const float* __restrict__ b3v, const float* __restrict__ h1obs,
    float* __restrict__ out)
{
    __shared__ float Acts[32][36];     // 32 tokens x 32 act dims (pad 36)
    __shared__ float W1s[32 * 128];    // act-part of W1 (rows 256..287)
    __shared__ float W2s[128 * 64];
    __shared__ float Hs[32][132];      // h1, pad 132
    __shared__ float H2s[32][68];      // h2, pad 68

    const int tid = threadIdx.x;
    const int g0  = blockIdx.x * 32;

    // GEMM1 mapping: 32x128 out, thread tile 4x4
    const int rb1 = tid >> 5, cb1 = tid & 31;
    // GEMM2 mapping: 32x64 out, thread tile 2x4
    const int rb2 = tid >> 4, cb2 = tid & 15;
    // GEMM3 mapping: 32x32 out, thread tile 1x4
    const int r3 = tid >> 3, cb3 = tid & 7;

    // stage W1 act-part (rows 256..287 contiguous) and W2
    #pragma unroll
    for (int u = 0; u < 4; ++u)
        *(f4*)(W1s + u * 1024 + tid * 4) =
            *(const f4*)(W1 + OBSD * H1D + u * 1024 + tid * 4);
    #pragma unroll
    for (int u = 0; u < 8; ++u)
        *(f4*)(W2s + u * 1024 + tid * 4) =
            *(const f4*)(W2 + u * 1024 + tid * 4);

    // h1_obs fragment in registers (GEMM1 mapping; includes b1)
    f4 hobs[4];
    #pragma unroll
    for (int i = 0; i < 4; ++i)
        hobs[i] = *(const f4*)(h1obs + (g0 + rb1 * 4 + i) * H1D + cb1 * 4);

    f4 bias2 = *(const f4*)(b2v + cb2 * 4);
    f4 bias3 = *(const f4*)(b3v + cb3 * 4);

    // act staging indices
    const int atok = tid >> 3;          // token 0..31
    const int aa   = (tid & 7) * 4;     // act dim 0..28
    const int g_at = g0 + atok;
    const int n_at = g_at & (NAG - 1);
    const int bt_at = g_at >> 4;

    f4 pw = {0.f, 0.f, 0.f, 0.f};       // p_with
    f4 pq = {0.f, 0.f, 0.f, 0.f};       // sum for p_without

    __syncthreads();

    for (int e = 0; e < NEVAL; ++e) {
        // --- stage action tile (e==1 is the all-zero action: skip) ---
        if (e != 1) {
            const float* src;
            if (e == 0) src = actions + g_at * ACTD + aa;
            else        src = cf + ((n_at * SCF + (e - 2)) * BT + bt_at) * ACTD + aa;
            f4 v = *(const f4*)src;
            *(f4*)(&Acts[atok][aa]) = v;
        }
        __syncthreads();  // B1

        // --- GEMM1: a1 = act @ W1a ; h1 = relu(h1_obs + a1) -> Hs ---
        f4 hval[4];
        if (e != 1) {
            float acc[4][4] = {};
            #pragma unroll
            for (int k0 = 0; k0 < ACTD; k0 += 4) {
                f4 a[4], b[4];
                #pragma unroll
                for (int i = 0; i < 4; ++i) a[i] = *(const f4*)(&Acts[rb1 * 4 + i][k0]);
                #pragma unroll
                for (int kk = 0; kk < 4; ++kk) b[kk] = *(const f4*)(W1s + (k0 + kk) * H1D + cb1 * 4);
                #pragma unroll
                for (int i = 0; i < 4; ++i)
                    #pragma unroll
                    for (int kk = 0; kk < 4; ++kk)
                        #pragma unroll
                        for (int j = 0; j < 4; ++j)
                            acc[i][j] = fmaf(a[i][kk], b[kk][j], acc[i][j]);
            }
            #pragma unroll
            for (int i = 0; i < 4; ++i)
                #pragma unroll
                for (int j = 0; j < 4; ++j)
                    hval[i][j] = fmaxf(hobs[i][j] + acc[i][j], 0.f);
        } else {
            #pragma unroll
            for (int i = 0; i < 4; ++i)
                #pragma unroll
                for (int j = 0; j < 4; ++j)
                    hval[i][j] = fmaxf(hobs[i][j], 0.f);
        }
        #pragma unroll
        for (int i = 0; i < 4; ++i)
            *(f4*)(&Hs[rb1 * 4 + i][cb1 * 4]) = hval[i];
        __syncthreads();  // B2

        // --- GEMM2: h2 = relu(h1 @ W2 + b2) -> H2s ---
        {
            float acc[2][4] = {};
            #pragma unroll 8
            for (int k0 = 0; k0 < H1D; k0 += 4) {
                f4 a0 = *(const f4*)(&Hs[rb2 * 2][k0]);
                f4 a1 = *(const f4*)(&Hs[rb2 * 2 + 1][k0]);
                f4 b[4];
                #pragma unroll
                for (int kk = 0; kk < 4; ++kk) b[kk] = *(const f4*)(W2s + (k0 + kk) * H2D + cb2 * 4);
                #pragma unroll
                for (int kk = 0; kk < 4; ++kk)
                    #pragma unroll
                    for (int j = 0; j < 4; ++j) {
                        acc[0][j] = fmaf(a0[kk], b[kk][j], acc[0][j]);
                        acc[1][j] = fmaf(a1[kk], b[kk][j], acc[1][j]);
                    }
            }
            #pragma unroll
            for (int i = 0; i < 2; ++i) {
                f4 v;
                #pragma unroll
                for (int j = 0; j < 4; ++j) v[j] = fmaxf(acc[i][j] + bias2[j], 0.f);
                *(f4*)(&H2s[rb2 * 2 + i][cb2 * 4]) = v;
            }
        }
        __syncthreads();  // B3

        // --- GEMM3: p = h2 @ W3 + b3 (W3 via L1) ---
        {
            f4 acc = {0.f, 0.f, 0.f, 0.f};
            #pragma unroll 8
            for (int k0 = 0; k0 < H2D; k0 += 4) {
                f4 a = *(const f4*)(&H2s[r3][k0]);
                #pragma unroll
                for (int kk = 0; kk < 4; ++kk) {
                    f4 b = *(const f4*)(W3 + (k0 + kk) * ACTD + cb3 * 4);
                    #pragma unroll
                    for (int j = 0; j < 4; ++j)
                        acc[j] = fmaf(a[kk], b[j], acc[j]);
                }
            }
            #pragma unroll
            for (int j = 0; j < 4; ++j) acc[j] += bias3[j];
            if (e == 0) pw = acc;
            else {
                #pragma unroll
                for (int j = 0; j < 4; ++j) pq[j] += acc[j];
            }
        }
        // no barrier needed here: Acts/Hs/H2s rewrites are >=1 barrier away
    }

    // --- KL: q*(log_q - log_p), mean over 32 action dims ---
    const float inv17 = 1.0f / 17.0f;
    f4 qv;
    #pragma unroll
    for (int j = 0; j < 4; ++j) qv[j] = pq[j] * inv17;

    float mw = fmaxf(fmaxf(pw[0], pw[1]), fmaxf(pw[2], pw[3]));
    float mq = fmaxf(fmaxf(qv[0], qv[1]), fmaxf(qv[2], qv[3]));
    #pragma unroll
    for (int m = 1; m < 8; m <<= 1) {
        mw = fmaxf(mw, __shfl_xor(mw, m));
        mq = fmaxf(mq, __shfl_xor(mq, m));
    }
    float sw = 0.f, sq = 0.f;
    #pragma unroll
    for (int j = 0; j < 4; ++j) {
        sw += expf(pw[j] - mw);
        sq += expf(qv[j] - mq);
    }
    #pragma unroll
    for (int m = 1; m < 8; m <<= 1) {
        sw += __shfl_xor(sw, m);
        sq += __shfl_xor(sq, m);
    }
    const float lsw = logf(sw), lsq = logf(sq);
    float kl = 0.f;
    #pragma unroll
    for (int j = 0; j < 4; ++j) {
        float lq = qv[j] - mq - lsq;
        float lp = pw[j] - mw - lsw;
        float q  = expf(lq);
        kl += q * (lq - lp);
    }
    #pragma unroll
    for (int m = 1; m < 8; m <<= 1) kl += __shfl_xor(kl, m);

    if (cb3 == 0) out[g0 + r3] = kl * (1.0f / 32.0f);
}

// ---------------------------------------------------------------------------
extern "C" void kernel_launch(void* const* d_in, const int* in_sizes, int n_in,
                              void* d_out, int out_size, void* d_ws, size_t ws_size,
                              hipStream_t stream)
{
    const float* obs     = (const float*)d_in[0];
    const float* actions = (const float*)d_in[1];
    const float* cf      = (const float*)d_in[2];
    const float* W1      = (const float*)d_in[3];
    const float* b1      = (const float*)d_in[4];
    const float* W2      = (const float*)d_in[5];
    const float* b2      = (const float*)d_in[6];
    const float* W3      = (const float*)d_in[7];
    const float* b3      = (const float*)d_in[8];
    float* outp  = (float*)d_out;
    float* h1obs = (float*)d_ws;   // 16384 x 128 fp32 = 8.39 MB scratch

    k_h1obs<<<NTOK / 32, 256, 0, stream>>>(obs, W1, b1, h1obs);
    k_main <<<NTOK / 32, 256, 0, stream>>>(actions, cf, W1, W2, b2, W3, b3,
                                           h1obs, outp);
}